// Round 1
// baseline (1064.449 us; speedup 1.0000x reference)
//
#include <hip/hip_runtime.h>
#include <math.h>

#define BB 4
#define TP 8192
#define TT 8193          // TP + 1
#define EE 4096
#define HH 32
#define HKV 8
#define DD 128
#define MM 256
#define GG 4             // H / HKV
#define NSEG 48          // H + 2*HKV row-segments of 128 for fused QKV GEMV
#define NTILE 257        // ceil(8193/32) key tiles per (b,kv)
#define WCH 65           // ceil(8193/128) value chunks per (b,kv)

#define CJL 0.0048957583420918762f     // sqrt(pi/2)/256
#define RSQRT_D 0.08838834764831845f   // 1/sqrt(128)
#define NEG_HUGE -3.402823466e38f

// ---- workspace layout (float offsets) ----
#define OFF_Q      0            // q_rope   B*H*D   = 16384
#define OFF_KN     16384        // k_new    B*HKV*D = 4096
#define OFF_VN     20480        // v_new              4096
#define OFF_SCORE  24576        // |k| sums           4096   (atomic, zeroed)
#define OFF_MASKF  28672        // 1-omask            4096
#define OFF_QS     32768        // qs       B*HKV*G*M = 32768
#define OFF_QOV    65536        // q at outlier dims  1024
#define OFF_AO     66560        // attn out B*H*D  = 16384   (atomic, zeroed)
#define OFF_LOGITS 82944        // B*HKV*G*T = 1048704
#define OFF_INT    1131648      // ints: pos (4096), oidx (256)

// ===================== 1. fused QKV GEMV + RoPE =====================
// grid = B*48, block 256. Each block: one 128-row head-segment, 2 threads/row.
__global__ __launch_bounds__(256) void qkv_rope_kernel(
    const float* __restrict__ hs, const float* __restrict__ cosb,
    const float* __restrict__ sinb, const float* __restrict__ Wq,
    const float* __restrict__ Wk, const float* __restrict__ Wv,
    float* __restrict__ q_out, float* __restrict__ k_out, float* __restrict__ v_out)
{
  int b = blockIdx.x / NSEG;
  int seg = blockIdx.x % NSEG;
  const float* W;
  if (seg < HH)            W = Wq + (size_t)seg * DD * EE;
  else if (seg < HH + HKV) W = Wk + (size_t)(seg - HH) * DD * EE;
  else                     W = Wv + (size_t)(seg - HH - HKV) * DD * EE;

  __shared__ float hsl[EE];
  __shared__ float part[DD][2];
  __shared__ float comb[DD];
  for (int i = threadIdx.x; i < EE; i += 256) hsl[i] = hs[b * EE + i];
  __syncthreads();
  int row = threadIdx.x & 127;
  int half = threadIdx.x >> 7;
  const float* wr = W + (size_t)row * EE + half * (EE / 2);
  const float* hv = hsl + half * (EE / 2);
  float acc = 0.f;
  for (int j = 0; j < EE / 2; j += 4) {
    float4 w4 = *(const float4*)(wr + j);
    float4 h4 = *(const float4*)(hv + j);
    acc = fmaf(w4.x, h4.x, acc);
    acc = fmaf(w4.y, h4.y, acc);
    acc = fmaf(w4.z, h4.z, acc);
    acc = fmaf(w4.w, h4.w, acc);
  }
  part[row][half] = acc;
  __syncthreads();
  if (threadIdx.x < DD) comb[threadIdx.x] = part[threadIdx.x][0] + part[threadIdx.x][1];
  __syncthreads();
  if (threadIdx.x < DD) {
    int d = threadIdx.x;
    float v = comb[d];
    if (seg >= HH + HKV) {
      v_out[((size_t)b * HKV + (seg - HH - HKV)) * DD + d] = v;
    } else {
      // RoPE: q' = q*c + rotate_half(q)*s ; rot[d<64] = -q[d+64], rot[d>=64] = q[d-64]
      float c = cosb[b * DD + d], s = sinb[b * DD + d];
      float other = (d < 64) ? -comb[d + 64] : comb[d - 64];
      float r = fmaf(v, c, other * s);
      if (seg < HH) q_out[((size_t)b * HH + seg) * DD + d] = r;
      else          k_out[((size_t)b * HKV + (seg - HH)) * DD + d] = r;
    }
  }
}

// ===================== 2. channel score: sum_t |K[t,d]| =====================
// grid = B*HKV*64 chunks, block 256 (128 d-lanes x 2 t-subs)
__global__ __launch_bounds__(256) void score_kernel(
    const float* __restrict__ pk, float* __restrict__ score)
{
  int chunk = blockIdx.x & 63;
  int bk = blockIdx.x >> 6;
  const float* base = pk + (size_t)bk * TP * DD;
  int d = threadIdx.x & 127, sub = threadIdx.x >> 7;
  int t0 = chunk * 128;
  float acc = 0.f;
  for (int t = t0 + sub; t < t0 + 128; t += 2)
    acc += fabsf(base[(size_t)t * DD + d]);
  __shared__ float red[2][DD];
  red[sub][d] = acc;
  __syncthreads();
  if (threadIdx.x < DD)
    atomicAdd(&score[bk * DD + d], red[0][d] + red[1][d]);
}

// ===================== 3. top-8 outlier channels =====================
// grid = B*HKV, block 128. Tie-break: smaller index wins (jax.lax.top_k).
__global__ __launch_bounds__(128) void topk_kernel(
    const float* __restrict__ score, const float* __restrict__ k_new,
    float* __restrict__ maskf, int* __restrict__ pos, int* __restrict__ oidx)
{
  int bk = blockIdx.x;
  int tid = threadIdx.x;
  __shared__ float sv[DD];
  __shared__ int si[DD];
  float cur = score[bk * DD + tid] + fabsf(k_new[bk * DD + tid]);
  maskf[bk * DD + tid] = 1.f;
  pos[bk * DD + tid] = -1;
  for (int o = 0; o < 8; ++o) {
    sv[tid] = cur; si[tid] = tid;
    __syncthreads();
    for (int st = 64; st > 0; st >>= 1) {
      if (tid < st) {
        float a = sv[tid], c = sv[tid + st];
        int ia = si[tid], ic = si[tid + st];
        if (c > a || (c == a && ic < ia)) { sv[tid] = c; si[tid] = ic; }
      }
      __syncthreads();
    }
    int mi = si[0];
    __syncthreads();
    if (tid == 0) oidx[bk * 8 + o] = mi;
    if (tid == mi) { pos[bk * DD + tid] = o; maskf[bk * DD + tid] = 0.f; cur = NEG_HUGE; }
  }
}

// ===================== 4. qs = q_in @ S ; q values at outlier dims ===========
// grid = B*HKV*G, block 256 (one m per thread)
__global__ __launch_bounds__(256) void qs_kernel(
    const float* __restrict__ q_rope, const float* __restrict__ maskf,
    const float* __restrict__ Sp, const int* __restrict__ oidx,
    float* __restrict__ qs, float* __restrict__ qoval)
{
  int bkg = blockIdx.x;
  int bk = bkg >> 2, g = bkg & 3;
  int b = bk >> 3, kv = bk & 7;
  __shared__ float qin[DD];
  __shared__ float qfull[DD];
  if (threadIdx.x < DD) {
    float qv = q_rope[((size_t)b * HH + kv * GG + g) * DD + threadIdx.x];
    qfull[threadIdx.x] = qv;
    qin[threadIdx.x] = qv * maskf[bk * DD + threadIdx.x];
  }
  __syncthreads();
  int m = threadIdx.x;
  float acc = 0.f;
  for (int d = 0; d < DD; ++d)
    acc = fmaf(qin[d], Sp[d * MM + m], acc);
  qs[(size_t)bkg * MM + m] = acc;
  if (threadIdx.x < 8)
    qoval[bkg * 8 + threadIdx.x] = qfull[oidx[bk * 8 + threadIdx.x]];
}

// ===================== 5. the big one: logits = (est + exact)/sqrt(D) ========
// grid = B*HKV*257 tiles of 32 t, block 256 (4 waves x [8 t x 64 m-lanes x 4 m])
// LDS: S full fp32 (128 KB) + 32x128 key tile + small side buffers = ~150 KB.
__global__ __launch_bounds__(256) void logits_kernel(
    const float* __restrict__ pk, const float* __restrict__ k_new,
    const float* __restrict__ Sp, const float* __restrict__ qs,
    const float* __restrict__ qoval, const int* __restrict__ pos,
    const float* __restrict__ amask, float* __restrict__ logits)
{
  __shared__ float Sl[DD][MM];      // 131072 B
  __shared__ float kt[32][DD];      // 16384 B (k_in: outliers zeroed)
  __shared__ float qsl[GG][MM];     // 4096 B
  __shared__ float qovl[GG][8];
  __shared__ float koutl[32][8];    // original k at outlier dims
  __shared__ float norm2[32];
  __shared__ int   posl[DD];
  __shared__ float estbuf[4][32];

  int bk = blockIdx.x / NTILE;
  int tile = blockIdx.x % NTILE;
  int b = bk >> 3;
  int t0 = tile * 32;
  int tid = threadIdx.x;

  for (int i = tid; i < DD * MM; i += 256) ((float*)Sl)[i] = Sp[i];
  for (int i = tid; i < GG * MM; i += 256) ((float*)qsl)[i] = qs[(size_t)bk * GG * MM + i];
  if (tid < 32) ((float*)qovl)[tid] = qoval[bk * 32 + tid];
  if (tid < DD) posl[tid] = pos[bk * DD + tid];
  __syncthreads();

  // stage key tile: zero outlier channels, save originals, fused norms
  for (int iter = 0; iter < 4; ++iter) {
    int tl = iter * 8 + (tid >> 5);
    int d4 = (tid & 31) * 4;
    int tg = t0 + tl;
    float4 kv4 = make_float4(0.f, 0.f, 0.f, 0.f);
    if (tg < TP)       kv4 = *(const float4*)(pk + ((size_t)bk * TP + tg) * DD + d4);
    else if (tg == TP) kv4 = *(const float4*)(k_new + (size_t)bk * DD + d4);
    float vals[4] = {kv4.x, kv4.y, kv4.z, kv4.w};
    float nrm = 0.f;
    #pragma unroll
    for (int j = 0; j < 4; ++j) {
      int p = posl[d4 + j];
      if (p >= 0) { koutl[tl][p] = vals[j]; vals[j] = 0.f; }
      nrm = fmaf(vals[j], vals[j], nrm);
    }
    *(float4*)&kt[tl][d4] = make_float4(vals[0], vals[1], vals[2], vals[3]);
    #pragma unroll
    for (int off = 16; off > 0; off >>= 1) nrm += __shfl_xor(nrm, off);
    if ((tid & 31) == 0) norm2[tl] = nrm;
  }
  __syncthreads();

  int mq = tid & 63;   // m-lane: owns m = 4*mq .. 4*mq+3
  int tq = tid >> 6;   // wave: owns t = t0 + 8*tq .. +7
  float dot[8][4];
  #pragma unroll
  for (int j = 0; j < 8; ++j)
    #pragma unroll
    for (int i = 0; i < 4; ++i) dot[j][i] = 0.f;

  for (int d = 0; d < DD; ++d) {
    float4 s4 = *(const float4*)&Sl[d][mq * 4];   // ds_read_b128
    #pragma unroll
    for (int j = 0; j < 8; ++j) {
      float kvv = kt[tq * 8 + j][d];              // wave-uniform broadcast
      dot[j][0] = fmaf(kvv, s4.x, dot[j][0]);
      dot[j][1] = fmaf(kvv, s4.y, dot[j][1]);
      dot[j][2] = fmaf(kvv, s4.z, dot[j][2]);
      dot[j][3] = fmaf(kvv, s4.w, dot[j][3]);
    }
  }

  // est partials: sum_m qs[g,m]*sign(dot[m,t]) over this lane's 4 m's
  float4 qsv[GG];
  #pragma unroll
  for (int g = 0; g < GG; ++g) qsv[g] = *(const float4*)&qsl[g][mq * 4];
  float estp[8][GG];
  #pragma unroll
  for (int j = 0; j < 8; ++j) {
    float s0 = copysignf(1.f, dot[j][0]);
    float s1 = copysignf(1.f, dot[j][1]);
    float s2 = copysignf(1.f, dot[j][2]);
    float s3 = copysignf(1.f, dot[j][3]);
    #pragma unroll
    for (int g = 0; g < GG; ++g) {
      float e = qsv[g].x * s0;
      e = fmaf(qsv[g].y, s1, e);
      e = fmaf(qsv[g].z, s2, e);
      e = fmaf(qsv[g].w, s3, e);
      estp[j][g] = e;
    }
  }
  // reduce over all 64 m-lanes (covers all 256 m)
  #pragma unroll
  for (int j = 0; j < 8; ++j)
    #pragma unroll
    for (int g = 0; g < GG; ++g) {
      float v = estp[j][g];
      #pragma unroll
      for (int off = 32; off > 0; off >>= 1) v += __shfl_xor(v, off);
      estp[j][g] = v;
    }
  if (mq == 0) {
    #pragma unroll
    for (int j = 0; j < 8; ++j)
      #pragma unroll
      for (int g = 0; g < GG; ++g) estbuf[tq][j * 4 + g] = estp[j][g];
  }
  __syncthreads();
  if (mq < 32) {
    int g = mq >> 3, j = mq & 7;     // consecutive lanes -> consecutive t
    int tg = t0 + tq * 8 + j;
    if (tg < TT) {
      float est = estbuf[tq][j * 4 + g];
      float ex = 0.f;
      #pragma unroll
      for (int o = 0; o < 8; ++o) ex = fmaf(qovl[g][o], koutl[tq * 8 + j][o], ex);
      float nrm = sqrtf(norm2[tq * 8 + j]);
      float logit = fmaf(est * CJL, nrm, ex) * RSQRT_D;
      logit += (1.f - amask[b * TT + tg]) * NEG_HUGE;
      logits[((size_t)bk * GG + g) * TT + tg] = logit;
    }
  }
}

// ===================== 6. softmax over T per (b,kv,g) =====================
__global__ __launch_bounds__(256) void softmax_kernel(float* __restrict__ logits)
{
  int row = blockIdx.x;
  float* L = logits + (size_t)row * TT;
  int tid = threadIdx.x;
  int lane = tid & 63, wid = tid >> 6;
  __shared__ float red[8];
  float mx = NEG_HUGE;
  for (int i = tid; i < TT; i += 256) mx = fmaxf(mx, L[i]);
  #pragma unroll
  for (int off = 32; off > 0; off >>= 1) mx = fmaxf(mx, __shfl_xor(mx, off));
  if (lane == 0) red[wid] = mx;
  __syncthreads();
  if (tid == 0) red[4] = fmaxf(fmaxf(red[0], red[1]), fmaxf(red[2], red[3]));
  __syncthreads();
  mx = red[4];
  float sum = 0.f;
  for (int i = tid; i < TT; i += 256) sum += expf(L[i] - mx);
  #pragma unroll
  for (int off = 32; off > 0; off >>= 1) sum += __shfl_xor(sum, off);
  if (lane == 0) red[wid] = sum;
  __syncthreads();
  if (tid == 0) red[5] = (red[0] + red[1]) + (red[2] + red[3]);
  __syncthreads();
  float inv = 1.f / red[5];
  for (int i = tid; i < TT; i += 256) L[i] = expf(L[i] - mx) * inv;
}

// ===================== 7. out_head = w @ V (atomic partials) ================
// grid = B*HKV*65 chunks of 128 t, block 256 (128 d-lanes x 2 t-subs)
__global__ __launch_bounds__(256) void wv_kernel(
    const float* __restrict__ pv, const float* __restrict__ v_new,
    const float* __restrict__ w, float* __restrict__ attn_out)
{
  int bk = blockIdx.x / WCH;
  int chunk = blockIdx.x % WCH;
  int b = bk >> 3, kv = bk & 7;
  int d = threadIdx.x & 127, sub = threadIdx.x >> 7;
  int t0 = chunk * 128;
  int tend = (t0 + 128 < TT) ? t0 + 128 : TT;
  float acc[GG] = {0.f, 0.f, 0.f, 0.f};
  const float* wbase = w + (size_t)bk * GG * TT;
  for (int t = t0 + sub; t < tend; t += 2) {
    float v = (t < TP) ? pv[((size_t)bk * TP + t) * DD + d] : v_new[(size_t)bk * DD + d];
    #pragma unroll
    for (int g = 0; g < GG; ++g)
      acc[g] = fmaf(wbase[g * TT + t], v, acc[g]);
  }
  __shared__ float red[2][DD][GG];
  #pragma unroll
  for (int g = 0; g < GG; ++g) red[sub][d][g] = acc[g];
  __syncthreads();
  if (threadIdx.x < DD) {
    #pragma unroll
    for (int g = 0; g < GG; ++g)
      atomicAdd(&attn_out[((size_t)b * HH + kv * GG + g) * DD + d],
                red[0][d][g] + red[1][d][g]);
  }
}

// ===================== 8. final projection: out = attn_out @ Wo^T ============
// grid = B*32, block 256
__global__ __launch_bounds__(256) void outproj_kernel(
    const float* __restrict__ attn_out, const float* __restrict__ Wo,
    float* __restrict__ out)
{
  int b = blockIdx.x >> 5;
  int seg = blockIdx.x & 31;
  __shared__ float al[EE];
  __shared__ float part[DD][2];
  for (int i = threadIdx.x; i < EE; i += 256) al[i] = attn_out[(size_t)b * EE + i];
  __syncthreads();
  int row = threadIdx.x & 127, half = threadIdx.x >> 7;
  int e = seg * DD + row;
  const float* wr = Wo + (size_t)e * EE + half * (EE / 2);
  const float* av = al + half * (EE / 2);
  float acc = 0.f;
  for (int j = 0; j < EE / 2; j += 4) {
    float4 w4 = *(const float4*)(wr + j);
    float4 a4 = *(const float4*)(av + j);
    acc = fmaf(w4.x, a4.x, acc);
    acc = fmaf(w4.y, a4.y, acc);
    acc = fmaf(w4.z, a4.z, acc);
    acc = fmaf(w4.w, a4.w, acc);
  }
  part[row][half] = acc;
  __syncthreads();
  if (threadIdx.x < DD)
    out[(size_t)b * EE + seg * DD + threadIdx.x] = part[threadIdx.x][0] + part[threadIdx.x][1];
}

// ===================== launcher =====================
extern "C" void kernel_launch(void* const* d_in, const int* in_sizes, int n_in,
                              void* d_out, int out_size, void* d_ws, size_t ws_size,
                              hipStream_t stream)
{
  const float* hs    = (const float*)d_in[0];
  const float* cosb  = (const float*)d_in[1];
  const float* sinb  = (const float*)d_in[2];
  const float* pk    = (const float*)d_in[3];
  const float* pv    = (const float*)d_in[4];
  const float* amask = (const float*)d_in[5];
  const float* Wq    = (const float*)d_in[6];
  const float* Wk    = (const float*)d_in[7];
  const float* Wv    = (const float*)d_in[8];
  const float* Wo    = (const float*)d_in[9];
  const float* Sp    = (const float*)d_in[10];
  float* out = (float*)d_out;
  float* ws = (float*)d_ws;

  float* q_rope = ws + OFF_Q;
  float* k_new  = ws + OFF_KN;
  float* v_new  = ws + OFF_VN;
  float* score  = ws + OFF_SCORE;
  float* maskf  = ws + OFF_MASKF;
  float* qs     = ws + OFF_QS;
  float* qoval  = ws + OFF_QOV;
  float* attn_o = ws + OFF_AO;
  float* logits = ws + OFF_LOGITS;
  int* pos  = (int*)(ws + OFF_INT);
  int* oidx = pos + BB * HKV * DD;

  hipMemsetAsync(score, 0, BB * HKV * DD * sizeof(float), stream);
  hipMemsetAsync(attn_o, 0, BB * HH * DD * sizeof(float), stream);

  qkv_rope_kernel<<<BB * NSEG, 256, 0, stream>>>(hs, cosb, sinb, Wq, Wk, Wv,
                                                 q_rope, k_new, v_new);
  score_kernel<<<BB * HKV * 64, 256, 0, stream>>>(pk, score);
  topk_kernel<<<BB * HKV, 128, 0, stream>>>(score, k_new, maskf, pos, oidx);
  qs_kernel<<<BB * HKV * GG, 256, 0, stream>>>(q_rope, maskf, Sp, oidx, qs, qoval);
  logits_kernel<<<BB * HKV * NTILE, 256, 0, stream>>>(pk, k_new, Sp, qs, qoval,
                                                      pos, amask, logits);
  softmax_kernel<<<BB * HKV * GG, 256, 0, stream>>>(logits);
  wv_kernel<<<BB * HKV * WCH, 256, 0, stream>>>(pv, v_new, logits, attn_o);
  outproj_kernel<<<BB * 32, 256, 0, stream>>>(attn_o, Wo, out);
}

// Round 2
// 660.179 us; speedup vs baseline: 1.6124x; 1.6124x over previous
//
#include <hip/hip_runtime.h>
#include <math.h>

#define BB 4
#define TP 8192
#define TT 8193          // TP + 1
#define EE 4096
#define HH 32
#define HKV 8
#define DD 128
#define MM 256
#define GG 4             // H / HKV
#define NSEG 48          // H + 2*HKV row-segments of 128 for fused QKV GEMV
#define TB 64            // t-rows per logits block
#define NT2 129          // ceil(8193/64)
#define WCH 65           // ceil(8193/128) value chunks per (b,kv)

#define CJL 0.0048957583420918762f     // sqrt(pi/2)/256
#define RSQRT_D 0.08838834764831845f   // 1/sqrt(128)
#define NEG_HUGE -3.402823466e38f

#define KSTR 136         // kt row stride in f16 (128 + 8 pad; 272 B, 16B-aligned, 2-way banks)
#define SSTR 264         // sign row stride in f16 (528 B, 16B-aligned, 2-way banks)

typedef _Float16 f16x8 __attribute__((ext_vector_type(8)));
typedef _Float16 f16x4 __attribute__((ext_vector_type(4)));
typedef float f32x4 __attribute__((ext_vector_type(4)));

// ---- workspace layout (float offsets) ----
#define OFF_Q      0            // q_rope   B*H*D   = 16384
#define OFF_KN     16384        // k_new    B*HKV*D = 4096
#define OFF_VN     20480        // v_new              4096
#define OFF_SCORE  24576        // |k| sums           4096   (atomic, zeroed)
#define OFF_MASKF  28672        // 1-omask            4096
#define OFF_QS     32768        // qs       B*HKV*G*M = 32768
#define OFF_QOV    65536        // q at outlier dims  1024
#define OFF_AO     66560        // attn out B*H*D  = 16384   (atomic, zeroed)
#define OFF_LOGITS 82944        // B*HKV*G*T = 1048704
#define OFF_INT    1131648      // ints: pos (4096), oidx (256) -> 4352 floats
#define OFF_QSF    1136000      // qs as f16, padded [bk][16][256] = 131072 f16 = 65536 floats

// ===================== 1. fused QKV GEMV + RoPE =====================
__global__ __launch_bounds__(256) void qkv_rope_kernel(
    const float* __restrict__ hs, const float* __restrict__ cosb,
    const float* __restrict__ sinb, const float* __restrict__ Wq,
    const float* __restrict__ Wk, const float* __restrict__ Wv,
    float* __restrict__ q_out, float* __restrict__ k_out, float* __restrict__ v_out)
{
  int b = blockIdx.x / NSEG;
  int seg = blockIdx.x % NSEG;
  const float* W;
  if (seg < HH)            W = Wq + (size_t)seg * DD * EE;
  else if (seg < HH + HKV) W = Wk + (size_t)(seg - HH) * DD * EE;
  else                     W = Wv + (size_t)(seg - HH - HKV) * DD * EE;

  __shared__ float hsl[EE];
  __shared__ float part[DD][2];
  __shared__ float comb[DD];
  for (int i = threadIdx.x; i < EE; i += 256) hsl[i] = hs[b * EE + i];
  __syncthreads();
  int row = threadIdx.x & 127;
  int half = threadIdx.x >> 7;
  const float* wr = W + (size_t)row * EE + half * (EE / 2);
  const float* hv = hsl + half * (EE / 2);
  float acc = 0.f;
  for (int j = 0; j < EE / 2; j += 4) {
    float4 w4 = *(const float4*)(wr + j);
    float4 h4 = *(const float4*)(hv + j);
    acc = fmaf(w4.x, h4.x, acc);
    acc = fmaf(w4.y, h4.y, acc);
    acc = fmaf(w4.z, h4.z, acc);
    acc = fmaf(w4.w, h4.w, acc);
  }
  part[row][half] = acc;
  __syncthreads();
  if (threadIdx.x < DD) comb[threadIdx.x] = part[threadIdx.x][0] + part[threadIdx.x][1];
  __syncthreads();
  if (threadIdx.x < DD) {
    int d = threadIdx.x;
    float v = comb[d];
    if (seg >= HH + HKV) {
      v_out[((size_t)b * HKV + (seg - HH - HKV)) * DD + d] = v;
    } else {
      float c = cosb[b * DD + d], s = sinb[b * DD + d];
      float other = (d < 64) ? -comb[d + 64] : comb[d - 64];
      float r = fmaf(v, c, other * s);
      if (seg < HH) q_out[((size_t)b * HH + seg) * DD + d] = r;
      else          k_out[((size_t)b * HKV + (seg - HH)) * DD + d] = r;
    }
  }
}

// ===================== 2. channel score: sum_t |K[t,d]| =====================
__global__ __launch_bounds__(256) void score_kernel(
    const float* __restrict__ pk, float* __restrict__ score)
{
  int chunk = blockIdx.x & 63;
  int bk = blockIdx.x >> 6;
  const float* base = pk + (size_t)bk * TP * DD;
  int d = threadIdx.x & 127, sub = threadIdx.x >> 7;
  int t0 = chunk * 128;
  float acc = 0.f;
  for (int t = t0 + sub; t < t0 + 128; t += 2)
    acc += fabsf(base[(size_t)t * DD + d]);
  __shared__ float red[2][DD];
  red[sub][d] = acc;
  __syncthreads();
  if (threadIdx.x < DD)
    atomicAdd(&score[bk * DD + d], red[0][d] + red[1][d]);
}

// ===================== 3. top-8 outlier channels =====================
__global__ __launch_bounds__(128) void topk_kernel(
    const float* __restrict__ score, const float* __restrict__ k_new,
    float* __restrict__ maskf, int* __restrict__ pos, int* __restrict__ oidx)
{
  int bk = blockIdx.x;
  int tid = threadIdx.x;
  __shared__ float sv[DD];
  __shared__ int si[DD];
  float cur = score[bk * DD + tid] + fabsf(k_new[bk * DD + tid]);
  maskf[bk * DD + tid] = 1.f;
  pos[bk * DD + tid] = -1;
  for (int o = 0; o < 8; ++o) {
    sv[tid] = cur; si[tid] = tid;
    __syncthreads();
    for (int st = 64; st > 0; st >>= 1) {
      if (tid < st) {
        float a = sv[tid], c = sv[tid + st];
        int ia = si[tid], ic = si[tid + st];
        if (c > a || (c == a && ic < ia)) { sv[tid] = c; si[tid] = ic; }
      }
      __syncthreads();
    }
    int mi = si[0];
    __syncthreads();
    if (tid == 0) oidx[bk * 8 + o] = mi;
    if (tid == mi) { pos[bk * DD + tid] = o; maskf[bk * DD + tid] = 0.f; cur = NEG_HUGE; }
  }
}

// ===================== 4. qs = q_in @ S (fp32 + f16 padded copy) =============
__global__ __launch_bounds__(256) void qs_kernel(
    const float* __restrict__ q_rope, const float* __restrict__ maskf,
    const float* __restrict__ Sp, const int* __restrict__ oidx,
    float* __restrict__ qs, _Float16* __restrict__ qsfT,
    float* __restrict__ qoval)
{
  int bkg = blockIdx.x;
  int bk = bkg >> 2, g = bkg & 3;
  int b = bk >> 3, kv = bk & 7;
  __shared__ float qin[DD];
  __shared__ float qfull[DD];
  if (threadIdx.x < DD) {
    float qv = q_rope[((size_t)b * HH + kv * GG + g) * DD + threadIdx.x];
    qfull[threadIdx.x] = qv;
    qin[threadIdx.x] = qv * maskf[bk * DD + threadIdx.x];
  }
  __syncthreads();
  int m = threadIdx.x;
  float acc = 0.f;
  for (int d = 0; d < DD; ++d)
    acc = fmaf(qin[d], Sp[d * MM + m], acc);
  qs[(size_t)bkg * MM + m] = acc;
  qsfT[((size_t)bk * 16 + g) * MM + m] = (_Float16)acc;
  if (g == 0) {
    #pragma unroll
    for (int n = 4; n < 16; ++n)
      qsfT[((size_t)bk * 16 + n) * MM + m] = (_Float16)0.f;
  }
  if (threadIdx.x < 8)
    qoval[bkg * 8 + threadIdx.x] = qfull[oidx[bk * 8 + threadIdx.x]];
}

// ===================== 5. logits via f16 hi/lo MFMA =====================
// grid = 32 * 129, block 256 (4 waves). Wave w owns m in [64w, 64w+64).
// dot = k_hi*S_hi + k_lo*S_hi + k_hi*S_lo  (residual ~2^-22, sign-safe)
// est = sign-matrix (f16, exact) @ qs_f16 via second MFMA pass.
__global__ __launch_bounds__(256) void logits_kernel(
    const float* __restrict__ pk, const float* __restrict__ k_new,
    const float* __restrict__ Sp, const _Float16* __restrict__ qsfT,
    const float* __restrict__ qoval, const int* __restrict__ pos,
    const float* __restrict__ amask, float* __restrict__ logits)
{
  __shared__ union U {
    struct { _Float16 hi[TB * KSTR]; _Float16 lo[TB * KSTR]; } k;  // 34816 B
    _Float16 ssg[TB * SSTR];                                       // 33792 B
  } u;
  __shared__ float norm2[TB];
  __shared__ float koutl[TB][8];
  __shared__ float qovl[GG][8];
  __shared__ int   posl[DD];

  int bk = blockIdx.x / NT2;
  int tile = blockIdx.x % NT2;
  int b = bk >> 3;
  int t0 = tile * TB;
  int tid = threadIdx.x;
  int l15 = tid & 15;
  int q   = (tid >> 4) & 3;
  int w   = tid >> 6;
  int mb  = w * 64;

  if (tid < DD) posl[tid] = pos[bk * DD + tid];
  if (tid < 32) ((float*)qovl)[tid] = qoval[bk * 32 + tid];

  // ---- S fragments into registers (hi/lo f16), wave-private m-group ----
  f16x8 sh[4][4], sl[4][4];
  #pragma unroll
  for (int mt = 0; mt < 4; ++mt)
    #pragma unroll
    for (int ks = 0; ks < 4; ++ks)
      #pragma unroll
      for (int j = 0; j < 8; ++j) {
        float s = Sp[(ks * 32 + q * 8 + j) * MM + mb + mt * 16 + l15];
        _Float16 h = (_Float16)s;
        sh[mt][ks][j] = h;
        sl[mt][ks][j] = (_Float16)(s - (float)h);
      }

  // ---- stage key tile: zero outliers, save originals, norms, hi/lo cvt ----
  #pragma unroll
  for (int iter = 0; iter < 8; ++iter) {
    int tl = iter * 8 + (tid >> 5);
    int d4 = (tid & 31) * 4;
    int tg = t0 + tl;
    float4 kv4 = make_float4(0.f, 0.f, 0.f, 0.f);
    if (tg < TP)       kv4 = *(const float4*)(pk + ((size_t)bk * TP + tg) * DD + d4);
    else if (tg == TP) kv4 = *(const float4*)(k_new + (size_t)bk * DD + d4);
    float vals[4] = {kv4.x, kv4.y, kv4.z, kv4.w};
    float nrm = 0.f;
    f16x4 hi4, lo4;
    #pragma unroll
    for (int j = 0; j < 4; ++j) {
      int p = posl[d4 + j];
      if (p >= 0) { koutl[tl][p] = vals[j]; vals[j] = 0.f; }
      nrm = fmaf(vals[j], vals[j], nrm);
      _Float16 h = (_Float16)vals[j];
      hi4[j] = h;
      lo4[j] = (_Float16)(vals[j] - (float)h);
    }
    *(f16x4*)&u.k.hi[tl * KSTR + d4] = hi4;
    *(f16x4*)&u.k.lo[tl * KSTR + d4] = lo4;
    #pragma unroll
    for (int off = 16; off > 0; off >>= 1) nrm += __shfl_xor(nrm, off);
    if ((tid & 31) == 0) norm2[tl] = nrm;
  }
  __syncthreads();

  // ---- main MFMA loop: acc[ts][mt] = k-tile @ S(m-group) ----
  f32x4 acc[4][4];
  #pragma unroll
  for (int ts = 0; ts < 4; ++ts)
    #pragma unroll
    for (int mt = 0; mt < 4; ++mt)
      acc[ts][mt] = (f32x4){0.f, 0.f, 0.f, 0.f};

  #pragma unroll
  for (int ts = 0; ts < 4; ++ts) {
    #pragma unroll
    for (int ks = 0; ks < 4; ++ks) {
      f16x8 ah = *(const f16x8*)&u.k.hi[(ts * 16 + l15) * KSTR + ks * 32 + q * 8];
      f16x8 al = *(const f16x8*)&u.k.lo[(ts * 16 + l15) * KSTR + ks * 32 + q * 8];
      #pragma unroll
      for (int mt = 0; mt < 4; ++mt) {
        acc[ts][mt] = __builtin_amdgcn_mfma_f32_16x16x32_f16(ah, sh[mt][ks], acc[ts][mt], 0, 0, 0);
        acc[ts][mt] = __builtin_amdgcn_mfma_f32_16x16x32_f16(al, sh[mt][ks], acc[ts][mt], 0, 0, 0);
        acc[ts][mt] = __builtin_amdgcn_mfma_f32_16x16x32_f16(ah, sl[mt][ks], acc[ts][mt], 0, 0, 0);
      }
    }
  }
  __syncthreads();   // done reading kt; LDS reused for sign matrix

  // ---- write sign matrix (C-layout -> [t][m] f16) ----
  #pragma unroll
  for (int ts = 0; ts < 4; ++ts)
    #pragma unroll
    for (int mt = 0; mt < 4; ++mt)
      #pragma unroll
      for (int r = 0; r < 4; ++r) {
        int tl = ts * 16 + q * 4 + r;
        int mm = mb + mt * 16 + l15;
        u.ssg[tl * SSTR + mm] = acc[ts][mt][r] >= 0.f ? (_Float16)1.f : (_Float16)-1.f;
      }
  __syncthreads();

  // ---- est = sign @ qs^T via MFMA; wave w handles t in [16w, 16w+16) ----
  f32x4 eacc = (f32x4){0.f, 0.f, 0.f, 0.f};
  const _Float16* qrow = qsfT + ((size_t)bk * 16 + l15) * MM;
  #pragma unroll
  for (int ks = 0; ks < 8; ++ks) {
    f16x8 as = *(const f16x8*)&u.ssg[(16 * w + l15) * SSTR + ks * 32 + q * 8];
    f16x8 bq = *(const f16x8*)&qrow[ks * 32 + q * 8];
    eacc = __builtin_amdgcn_mfma_f32_16x16x32_f16(as, bq, eacc, 0, 0, 0);
  }

  // ---- assemble logits: lanes with l15 < 4 hold est for g = l15 ----
  if (l15 < 4) {
    int g = l15;
    #pragma unroll
    for (int r = 0; r < 4; ++r) {
      int tl = 16 * w + q * 4 + r;
      int tg = t0 + tl;
      if (tg < TT) {
        float ex = 0.f;
        #pragma unroll
        for (int o = 0; o < 8; ++o) ex = fmaf(qovl[g][o], koutl[tl][o], ex);
        float logit = fmaf(eacc[r] * CJL, sqrtf(norm2[tl]), ex) * RSQRT_D;
        logit += (1.f - amask[b * TT + tg]) * NEG_HUGE;
        logits[((size_t)(bk * GG + g)) * TT + tg] = logit;
      }
    }
  }
}

// ===================== 6. softmax over T per (b,kv,g) =====================
__global__ __launch_bounds__(256) void softmax_kernel(float* __restrict__ logits)
{
  int row = blockIdx.x;
  float* L = logits + (size_t)row * TT;
  int tid = threadIdx.x;
  int lane = tid & 63, wid = tid >> 6;
  __shared__ float red[8];
  float mx = NEG_HUGE;
  for (int i = tid; i < TT; i += 256) mx = fmaxf(mx, L[i]);
  #pragma unroll
  for (int off = 32; off > 0; off >>= 1) mx = fmaxf(mx, __shfl_xor(mx, off));
  if (lane == 0) red[wid] = mx;
  __syncthreads();
  if (tid == 0) red[4] = fmaxf(fmaxf(red[0], red[1]), fmaxf(red[2], red[3]));
  __syncthreads();
  mx = red[4];
  float sum = 0.f;
  for (int i = tid; i < TT; i += 256) sum += expf(L[i] - mx);
  #pragma unroll
  for (int off = 32; off > 0; off >>= 1) sum += __shfl_xor(sum, off);
  if (lane == 0) red[wid] = sum;
  __syncthreads();
  if (tid == 0) red[5] = (red[0] + red[1]) + (red[2] + red[3]);
  __syncthreads();
  float inv = 1.f / red[5];
  for (int i = tid; i < TT; i += 256) L[i] = expf(L[i] - mx) * inv;
}

// ===================== 7. out_head = w @ V (atomic partials) ================
__global__ __launch_bounds__(256) void wv_kernel(
    const float* __restrict__ pv, const float* __restrict__ v_new,
    const float* __restrict__ w, float* __restrict__ attn_out)
{
  int bk = blockIdx.x / WCH;
  int chunk = blockIdx.x % WCH;
  int b = bk >> 3, kv = bk & 7;
  int d = threadIdx.x & 127, sub = threadIdx.x >> 7;
  int t0 = chunk * 128;
  int tend = (t0 + 128 < TT) ? t0 + 128 : TT;
  float acc[GG] = {0.f, 0.f, 0.f, 0.f};
  const float* wbase = w + (size_t)bk * GG * TT;
  for (int t = t0 + sub; t < tend; t += 2) {
    float v = (t < TP) ? pv[((size_t)bk * TP + t) * DD + d] : v_new[(size_t)bk * DD + d];
    #pragma unroll
    for (int g = 0; g < GG; ++g)
      acc[g] = fmaf(wbase[g * TT + t], v, acc[g]);
  }
  __shared__ float red[2][DD][GG];
  #pragma unroll
  for (int g = 0; g < GG; ++g) red[sub][d][g] = acc[g];
  __syncthreads();
  if (threadIdx.x < DD) {
    #pragma unroll
    for (int g = 0; g < GG; ++g)
      atomicAdd(&attn_out[((size_t)b * HH + kv * GG + g) * DD + d],
                red[0][d][g] + red[1][d][g]);
  }
}

// ===================== 8. final projection: out = attn_out @ Wo^T ============
__global__ __launch_bounds__(256) void outproj_kernel(
    const float* __restrict__ attn_out, const float* __restrict__ Wo,
    float* __restrict__ out)
{
  int b = blockIdx.x >> 5;
  int seg = blockIdx.x & 31;
  __shared__ float al[EE];
  __shared__ float part[DD][2];
  for (int i = threadIdx.x; i < EE; i += 256) al[i] = attn_out[(size_t)b * EE + i];
  __syncthreads();
  int row = threadIdx.x & 127, half = threadIdx.x >> 7;
  int e = seg * DD + row;
  const float* wr = Wo + (size_t)e * EE + half * (EE / 2);
  const float* av = al + half * (EE / 2);
  float acc = 0.f;
  for (int j = 0; j < EE / 2; j += 4) {
    float4 w4 = *(const float4*)(wr + j);
    float4 a4 = *(const float4*)(av + j);
    acc = fmaf(w4.x, a4.x, acc);
    acc = fmaf(w4.y, a4.y, acc);
    acc = fmaf(w4.z, a4.z, acc);
    acc = fmaf(w4.w, a4.w, acc);
  }
  part[row][half] = acc;
  __syncthreads();
  if (threadIdx.x < DD)
    out[(size_t)b * EE + seg * DD + threadIdx.x] = part[threadIdx.x][0] + part[threadIdx.x][1];
}

// ===================== launcher =====================
extern "C" void kernel_launch(void* const* d_in, const int* in_sizes, int n_in,
                              void* d_out, int out_size, void* d_ws, size_t ws_size,
                              hipStream_t stream)
{
  const float* hs    = (const float*)d_in[0];
  const float* cosb  = (const float*)d_in[1];
  const float* sinb  = (const float*)d_in[2];
  const float* pk    = (const float*)d_in[3];
  const float* pv    = (const float*)d_in[4];
  const float* amask = (const float*)d_in[5];
  const float* Wq    = (const float*)d_in[6];
  const float* Wk    = (const float*)d_in[7];
  const float* Wv    = (const float*)d_in[8];
  const float* Wo    = (const float*)d_in[9];
  const float* Sp    = (const float*)d_in[10];
  float* out = (float*)d_out;
  float* ws = (float*)d_ws;

  float* q_rope = ws + OFF_Q;
  float* k_new  = ws + OFF_KN;
  float* v_new  = ws + OFF_VN;
  float* score  = ws + OFF_SCORE;
  float* maskf  = ws + OFF_MASKF;
  float* qs     = ws + OFF_QS;
  float* qoval  = ws + OFF_QOV;
  float* attn_o = ws + OFF_AO;
  float* logits = ws + OFF_LOGITS;
  int* pos  = (int*)(ws + OFF_INT);
  int* oidx = pos + BB * HKV * DD;
  _Float16* qsfT = (_Float16*)(ws + OFF_QSF);

  hipMemsetAsync(score, 0, BB * HKV * DD * sizeof(float), stream);
  hipMemsetAsync(attn_o, 0, BB * HH * DD * sizeof(float), stream);

  qkv_rope_kernel<<<BB * NSEG, 256, 0, stream>>>(hs, cosb, sinb, Wq, Wk, Wv,
                                                 q_rope, k_new, v_new);
  score_kernel<<<BB * HKV * 64, 256, 0, stream>>>(pk, score);
  topk_kernel<<<BB * HKV, 128, 0, stream>>>(score, k_new, maskf, pos, oidx);
  qs_kernel<<<BB * HKV * GG, 256, 0, stream>>>(q_rope, maskf, Sp, oidx, qs, qsfT, qoval);
  logits_kernel<<<BB * HKV * NT2, 256, 0, stream>>>(pk, k_new, Sp, qsfT, qoval,
                                                    pos, amask, logits);
  softmax_kernel<<<BB * HKV * GG, 256, 0, stream>>>(logits);
  wv_kernel<<<BB * HKV * WCH, 256, 0, stream>>>(pv, v_new, logits, attn_o);
  outproj_kernel<<<BB * 32, 256, 0, stream>>>(attn_o, Wo, out);
}

// Round 3
// 583.425 us; speedup vs baseline: 1.8245x; 1.1316x over previous
//
#include <hip/hip_runtime.h>
#include <math.h>

#define BB 4
#define TP 8192
#define TT 8193          // TP + 1
#define EE 4096
#define HH 32
#define HKV 8
#define DD 128
#define MM 256
#define GG 4             // H / HKV
#define NSEG 48          // H + 2*HKV row-segments of 128
#define ESPLIT 4         // E-split for qkv GEMV
#define TB 64            // t-rows per logits block
#define NT2 129          // ceil(8193/64)
#define WCH 65           // ceil(8193/128) value chunks per (b,kv)

#define CJL 0.0048957583420918762f     // sqrt(pi/2)/256
#define RSQRT_D 0.08838834764831845f   // 1/sqrt(128)
#define NEG_HUGE -3.402823466e38f

#define KSTR 136         // kt row stride in f16
#define SSTR 276         // sign row stride in f16 (552 B: conflict-free b16 writes)

typedef _Float16 f16x8 __attribute__((ext_vector_type(8)));
typedef _Float16 f16x4 __attribute__((ext_vector_type(4)));
typedef float f32x4 __attribute__((ext_vector_type(4)));

// ---- workspace layout (float offsets) ----
#define OFF_Q      0            // q_rope   B*H*D    = 16384
#define OFF_KN     16384        // k_new    B*HKV*D  = 4096
#define OFF_VN     20480        // v_new               4096
#define OFF_MASKF  24576        // 1-omask             4096
#define OFF_QOV    28672        // q at outlier dims   1024
#define OFF_AO     29696        // attn out B*H*D    = 16384 (zeroed in softmax)
#define OFF_INT    46080        // ints: pos (4096), oidx (256) -> 4352 floats
#define OFF_QSF    50432        // qs f16 padded [bk][16][256] = 131072 f16 = 65536 fl
#define OFF_SFRAG  115968       // S frags: hi 65536 f16 + lo 65536 f16 = 65536 fl
#define OFF_QKVP   181504       // qkv partials [4][B][48][128] = 98304 fl
#define OFF_SCOREP 279808       // score partials [64][32][128] = 262144 fl
#define OFF_LOGITS 541952       // B*HKV*G*T = 1048704 fl

// ============ K1: fused qkv-partial GEMV + score partials + S-frag prep ======
// blocks [0,768): qkv E-split partials; [768,2816): score; [2816,2832): sprep
__global__ __launch_bounds__(256) void k1_kernel(
    const float* __restrict__ hs, const float* __restrict__ pk,
    const float* __restrict__ Wq, const float* __restrict__ Wk,
    const float* __restrict__ Wv, const float* __restrict__ Sp,
    float* __restrict__ qkvp, float* __restrict__ scorep,
    _Float16* __restrict__ Sfhi, _Float16* __restrict__ Sflo)
{
  __shared__ float shl[1024];
  __shared__ float sred[256];
  int bid = blockIdx.x, tid = threadIdx.x;
  if (bid < BB * NSEG * ESPLIT) {
    // ---- qkv partial: (c, b, seg); 128 rows x 1024-E-chunk, 2 thr/row ----
    int c = bid & 3;
    int id = bid >> 2;
    int b = id / NSEG, seg = id % NSEG;
    const float* W;
    if (seg < HH)            W = Wq + (size_t)seg * DD * EE;
    else if (seg < HH + HKV) W = Wk + (size_t)(seg - HH) * DD * EE;
    else                     W = Wv + (size_t)(seg - HH - HKV) * DD * EE;
    for (int i = tid; i < 1024; i += 256) shl[i] = hs[b * EE + c * 1024 + i];
    __syncthreads();
    int row = tid & 127, half = tid >> 7;
    const float* wr = W + (size_t)row * EE + c * 1024 + half * 512;
    const float* hv = shl + half * 512;
    float acc = 0.f;
    for (int j = 0; j < 512; j += 4) {
      float4 w4 = *(const float4*)(wr + j);
      float4 h4 = *(const float4*)(hv + j);
      acc = fmaf(w4.x, h4.x, acc);
      acc = fmaf(w4.y, h4.y, acc);
      acc = fmaf(w4.z, h4.z, acc);
      acc = fmaf(w4.w, h4.w, acc);
    }
    sred[half * 128 + row] = acc;
    __syncthreads();
    if (tid < 128)
      qkvp[((size_t)(c * BB + b) * NSEG + seg) * DD + tid] = sred[tid] + sred[128 + tid];
  } else if (bid < BB * NSEG * ESPLIT + BB * HKV * 64) {
    // ---- score partial: sum_t |K[t,d]| over a 128-t chunk ----
    int id = bid - BB * NSEG * ESPLIT;
    int chunk = id & 63, bk = id >> 6;
    const float* base = pk + (size_t)bk * TP * DD;
    int d = tid & 127, sub = tid >> 7;
    int t0 = chunk * 128;
    float acc = 0.f;
    for (int t = t0 + sub; t < t0 + 128; t += 2)
      acc += fabsf(base[(size_t)t * DD + d]);
    sred[sub * 128 + d] = acc;
    __syncthreads();
    if (tid < 128)
      scorep[((size_t)chunk * BB * HKV + bk) * DD + tid] = sred[tid] + sred[128 + tid];
  } else {
    // ---- sprep: S -> f16 hi/lo fragments in MFMA-lane-swizzled layout ----
    int id = bid - BB * NSEG * ESPLIT - BB * HKV * 64;   // 0..15 = mt*4+ks
    int mt = id >> 2, ks = id & 3;
    int w = tid >> 6, q = (tid >> 4) & 3, l15 = tid & 15;
    f16x8 hi, lo;
    #pragma unroll
    for (int j = 0; j < 8; ++j) {
      float s = Sp[(ks * 32 + q * 8 + j) * MM + w * 64 + mt * 16 + l15];
      _Float16 h = (_Float16)s;
      hi[j] = h;
      lo[j] = (_Float16)(s - (float)h);
    }
    *(f16x8*)&Sfhi[(size_t)(id * 256 + tid) * 8] = hi;
    *(f16x8*)&Sflo[(size_t)(id * 256 + tid) * 8] = lo;
  }
}

// ============ K2: qkv finalize — sum 4 partials + RoPE ============
// grid 96 x 256: one thread per output element (b, seg, d)
__global__ __launch_bounds__(256) void qkv_finalize_kernel(
    const float* __restrict__ qkvp, const float* __restrict__ cosb,
    const float* __restrict__ sinb, float* __restrict__ q_out,
    float* __restrict__ k_out, float* __restrict__ v_out)
{
  int gid = blockIdx.x * 256 + threadIdx.x;   // < 24576
  int b = gid / 6144;
  int r = gid - b * 6144;
  int seg = r >> 7, d = r & 127;
  float sum = 0.f;
  #pragma unroll
  for (int c = 0; c < 4; ++c)
    sum += qkvp[((size_t)(c * BB + b) * NSEG + seg) * DD + d];
  if (seg >= HH + HKV) {
    v_out[((size_t)b * HKV + (seg - HH - HKV)) * DD + d] = sum;
  } else {
    float part = 0.f;
    int dp = d ^ 64;
    #pragma unroll
    for (int c = 0; c < 4; ++c)
      part += qkvp[((size_t)(c * BB + b) * NSEG + seg) * DD + dp];
    float cc = cosb[b * DD + d], ss = sinb[b * DD + d];
    float other = (d < 64) ? -part : part;
    float rv = fmaf(sum, cc, other * ss);
    if (seg < HH) q_out[((size_t)b * HH + seg) * DD + d] = rv;
    else          k_out[((size_t)b * HKV + (seg - HH)) * DD + d] = rv;
  }
}

// ============ K3: top-8 outlier channels ============
__global__ __launch_bounds__(128) void topk_kernel(
    const float* __restrict__ scorep, const float* __restrict__ k_new,
    float* __restrict__ maskf, int* __restrict__ pos, int* __restrict__ oidx)
{
  int bk = blockIdx.x;
  int tid = threadIdx.x;
  __shared__ float sv[DD];
  __shared__ int si[DD];
  float cur = 0.f;
  for (int c = 0; c < 64; ++c)
    cur += scorep[((size_t)c * BB * HKV + bk) * DD + tid];
  cur += fabsf(k_new[bk * DD + tid]);
  maskf[bk * DD + tid] = 1.f;
  pos[bk * DD + tid] = -1;
  for (int o = 0; o < 8; ++o) {
    sv[tid] = cur; si[tid] = tid;
    __syncthreads();
    for (int st = 64; st > 0; st >>= 1) {
      if (tid < st) {
        float a = sv[tid], c2 = sv[tid + st];
        int ia = si[tid], ic = si[tid + st];
        if (c2 > a || (c2 == a && ic < ia)) { sv[tid] = c2; si[tid] = ic; }
      }
      __syncthreads();
    }
    int mi = si[0];
    __syncthreads();
    if (tid == 0) oidx[bk * 8 + o] = mi;
    if (tid == mi) { pos[bk * DD + tid] = o; maskf[bk * DD + tid] = 0.f; cur = NEG_HUGE; }
  }
}

// ============ K4: qs = q_in @ S (f16 padded) + q outlier values ============
__global__ __launch_bounds__(256) void qs_kernel(
    const float* __restrict__ q_rope, const float* __restrict__ maskf,
    const float* __restrict__ Sp, const int* __restrict__ oidx,
    _Float16* __restrict__ qsfT, float* __restrict__ qoval)
{
  int bkg = blockIdx.x;
  int bk = bkg >> 2, g = bkg & 3;
  int b = bk >> 3, kv = bk & 7;
  __shared__ float qin[DD];
  __shared__ float qfull[DD];
  if (threadIdx.x < DD) {
    float qv = q_rope[((size_t)b * HH + kv * GG + g) * DD + threadIdx.x];
    qfull[threadIdx.x] = qv;
    qin[threadIdx.x] = qv * maskf[bk * DD + threadIdx.x];
  }
  __syncthreads();
  int m = threadIdx.x;
  float acc = 0.f;
  for (int d = 0; d < DD; ++d)
    acc = fmaf(qin[d], Sp[d * MM + m], acc);
  qsfT[((size_t)bk * 16 + g) * MM + m] = (_Float16)acc;
  if (g == 0) {
    #pragma unroll
    for (int n = 4; n < 16; ++n)
      qsfT[((size_t)bk * 16 + n) * MM + m] = (_Float16)0.f;
  }
  if (threadIdx.x < 8)
    qoval[bkg * 8 + threadIdx.x] = qfull[oidx[bk * 8 + threadIdx.x]];
}

// ============ K5: logits via f16 hi/lo MFMA, S streamed per-ks ============
__global__ __launch_bounds__(256) void logits_kernel(
    const float* __restrict__ pk, const float* __restrict__ k_new,
    const _Float16* __restrict__ Sfhi, const _Float16* __restrict__ Sflo,
    const _Float16* __restrict__ qsfT, const float* __restrict__ qoval,
    const int* __restrict__ pos, const float* __restrict__ amask,
    float* __restrict__ logits)
{
  __shared__ union {
    struct { _Float16 hi[TB * KSTR]; _Float16 lo[TB * KSTR]; } k;  // 34816 B
    _Float16 ssg[TB * SSTR];                                       // 35328 B
  } u;
  __shared__ float norm2[TB];
  __shared__ float koutl[TB][8];
  __shared__ float qovl[GG][8];

  int bk = blockIdx.x / NT2;
  int tile = blockIdx.x % NT2;
  int b = bk >> 3;
  int t0 = tile * TB;
  int tid = threadIdx.x;
  int l15 = tid & 15;
  int q   = (tid >> 4) & 3;
  int w   = tid >> 6;
  int mb  = w * 64;

  if (tid < 32) ((float*)qovl)[tid] = qoval[bk * 32 + tid];

  // per-lane outlier positions for its 4 d's (constant across t-rows)
  int d4 = (tid & 31) * 4;
  int p4[4];
  #pragma unroll
  for (int j = 0; j < 4; ++j) p4[j] = pos[bk * DD + d4 + j];

  // ---- stage key tile: zero outliers, save originals, norms, hi/lo cvt ----
  #pragma unroll
  for (int iter = 0; iter < 8; ++iter) {
    int tl = iter * 8 + (tid >> 5);
    int tg = t0 + tl;
    float4 kv4 = make_float4(0.f, 0.f, 0.f, 0.f);
    if (tg < TP)       kv4 = *(const float4*)(pk + ((size_t)bk * TP + tg) * DD + d4);
    else if (tg == TP) kv4 = *(const float4*)(k_new + (size_t)bk * DD + d4);
    float vals[4] = {kv4.x, kv4.y, kv4.z, kv4.w};
    float nrm = 0.f;
    f16x4 hi4, lo4;
    #pragma unroll
    for (int j = 0; j < 4; ++j) {
      if (p4[j] >= 0) { koutl[tl][p4[j]] = vals[j]; vals[j] = 0.f; }
      nrm = fmaf(vals[j], vals[j], nrm);
      _Float16 h = (_Float16)vals[j];
      hi4[j] = h;
      lo4[j] = (_Float16)(vals[j] - (float)h);
    }
    *(f16x4*)&u.k.hi[tl * KSTR + d4] = hi4;
    *(f16x4*)&u.k.lo[tl * KSTR + d4] = lo4;
    #pragma unroll
    for (int off = 16; off > 0; off >>= 1) nrm += __shfl_xor(nrm, off);
    if ((tid & 31) == 0) norm2[tl] = nrm;
  }
  __syncthreads();

  // ---- MFMA loop: ks-chunked S streaming (8 frags resident at a time) ----
  f32x4 acc[4][4];
  #pragma unroll
  for (int ts = 0; ts < 4; ++ts)
    #pragma unroll
    for (int mt = 0; mt < 4; ++mt)
      acc[ts][mt] = (f32x4){0.f, 0.f, 0.f, 0.f};

  const f16x8* SH = (const f16x8*)Sfhi;
  const f16x8* SL = (const f16x8*)Sflo;
  #pragma unroll
  for (int ks = 0; ks < 4; ++ks) {
    f16x8 sh[4], sl[4], ah[4], al[4];
    #pragma unroll
    for (int mt = 0; mt < 4; ++mt) {
      sh[mt] = SH[(size_t)(mt * 4 + ks) * 256 + tid];
      sl[mt] = SL[(size_t)(mt * 4 + ks) * 256 + tid];
    }
    #pragma unroll
    for (int ts = 0; ts < 4; ++ts) {
      ah[ts] = *(const f16x8*)&u.k.hi[(ts * 16 + l15) * KSTR + ks * 32 + q * 8];
      al[ts] = *(const f16x8*)&u.k.lo[(ts * 16 + l15) * KSTR + ks * 32 + q * 8];
    }
    #pragma unroll
    for (int ts = 0; ts < 4; ++ts)
      #pragma unroll
      for (int mt = 0; mt < 4; ++mt) {
        acc[ts][mt] = __builtin_amdgcn_mfma_f32_16x16x32_f16(ah[ts], sh[mt], acc[ts][mt], 0, 0, 0);
        acc[ts][mt] = __builtin_amdgcn_mfma_f32_16x16x32_f16(al[ts], sh[mt], acc[ts][mt], 0, 0, 0);
        acc[ts][mt] = __builtin_amdgcn_mfma_f32_16x16x32_f16(ah[ts], sl[mt], acc[ts][mt], 0, 0, 0);
      }
  }
  __syncthreads();   // done reading kt; LDS reused for sign matrix

  // ---- write sign matrix (C-layout -> [t][m] f16) ----
  #pragma unroll
  for (int ts = 0; ts < 4; ++ts)
    #pragma unroll
    for (int mt = 0; mt < 4; ++mt)
      #pragma unroll
      for (int r = 0; r < 4; ++r) {
        int tl = ts * 16 + q * 4 + r;
        int mm = mb + mt * 16 + l15;
        u.ssg[tl * SSTR + mm] = acc[ts][mt][r] >= 0.f ? (_Float16)1.f : (_Float16)-1.f;
      }
  __syncthreads();

  // ---- est = sign @ qs^T via MFMA; wave w handles t in [16w, 16w+16) ----
  f32x4 eacc = (f32x4){0.f, 0.f, 0.f, 0.f};
  const _Float16* qrow = qsfT + ((size_t)bk * 16 + l15) * MM;
  #pragma unroll
  for (int ks = 0; ks < 8; ++ks) {
    f16x8 as = *(const f16x8*)&u.ssg[(16 * w + l15) * SSTR + ks * 32 + q * 8];
    f16x8 bq = *(const f16x8*)&qrow[ks * 32 + q * 8];
    eacc = __builtin_amdgcn_mfma_f32_16x16x32_f16(as, bq, eacc, 0, 0, 0);
  }

  // ---- assemble logits: lanes with l15 < 4 hold est for g = l15 ----
  if (l15 < 4) {
    int g = l15;
    #pragma unroll
    for (int r = 0; r < 4; ++r) {
      int tl = 16 * w + q * 4 + r;
      int tg = t0 + tl;
      if (tg < TT) {
        float ex = 0.f;
        #pragma unroll
        for (int o = 0; o < 8; ++o) ex = fmaf(qovl[g][o], koutl[tl][o], ex);
        float logit = fmaf(eacc[r] * CJL, sqrtf(norm2[tl]), ex) * RSQRT_D;
        logit += (1.f - amask[b * TT + tg]) * NEG_HUGE;
        logits[((size_t)(bk * GG + g)) * TT + tg] = logit;
      }
    }
  }
}

// ============ K6: softmax over T per (b,kv,g) + zero attn_o ============
__global__ __launch_bounds__(256) void softmax_kernel(
    float* __restrict__ logits, float* __restrict__ attn_o)
{
  int row = blockIdx.x;
  float* L = logits + (size_t)row * TT;
  int tid = threadIdx.x;
  int lane = tid & 63, wid = tid >> 6;
  __shared__ float red[8];
  if (tid < 128) attn_o[(size_t)row * DD + tid] = 0.f;
  float mx = NEG_HUGE;
  for (int i = tid; i < TT; i += 256) mx = fmaxf(mx, L[i]);
  #pragma unroll
  for (int off = 32; off > 0; off >>= 1) mx = fmaxf(mx, __shfl_xor(mx, off));
  if (lane == 0) red[wid] = mx;
  __syncthreads();
  if (tid == 0) red[4] = fmaxf(fmaxf(red[0], red[1]), fmaxf(red[2], red[3]));
  __syncthreads();
  mx = red[4];
  float sum = 0.f;
  for (int i = tid; i < TT; i += 256) sum += expf(L[i] - mx);
  #pragma unroll
  for (int off = 32; off > 0; off >>= 1) sum += __shfl_xor(sum, off);
  if (lane == 0) red[wid] = sum;
  __syncthreads();
  if (tid == 0) red[5] = (red[0] + red[1]) + (red[2] + red[3]);
  __syncthreads();
  float inv = 1.f / red[5];
  for (int i = tid; i < TT; i += 256) L[i] = expf(L[i] - mx) * inv;
}

// ============ K7: out_head = w @ V, float4 loads (atomic partials) ============
__global__ __launch_bounds__(256) void wv_kernel(
    const float* __restrict__ pv, const float* __restrict__ v_new,
    const float* __restrict__ w, float* __restrict__ attn_out)
{
  __shared__ float red[8][GG][DD];   // 16 KB
  int bk = blockIdx.x / WCH;
  int chunk = blockIdx.x % WCH;
  int b = bk >> 3, kv = bk & 7;
  int tsub = threadIdx.x >> 5;
  int d4 = (threadIdx.x & 31) * 4;
  int t0 = chunk * 128;
  int tend = (t0 + 128 < TT) ? t0 + 128 : TT;
  float4 acc[GG];
  #pragma unroll
  for (int g = 0; g < GG; ++g) acc[g] = make_float4(0.f, 0.f, 0.f, 0.f);
  const float* wbase = w + (size_t)bk * GG * TT;
  for (int t = t0 + tsub; t < tend; t += 8) {
    float4 v = (t < TP) ? *(const float4*)(pv + ((size_t)bk * TP + t) * DD + d4)
                        : *(const float4*)(v_new + (size_t)bk * DD + d4);
    #pragma unroll
    for (int g = 0; g < GG; ++g) {
      float wv = wbase[g * TT + t];
      acc[g].x = fmaf(wv, v.x, acc[g].x);
      acc[g].y = fmaf(wv, v.y, acc[g].y);
      acc[g].z = fmaf(wv, v.z, acc[g].z);
      acc[g].w = fmaf(wv, v.w, acc[g].w);
    }
  }
  #pragma unroll
  for (int g = 0; g < GG; ++g) *(float4*)&red[tsub][g][d4] = acc[g];
  __syncthreads();
  if (threadIdx.x < DD) {
    int d = threadIdx.x;
    #pragma unroll
    for (int g = 0; g < GG; ++g) {
      float s = 0.f;
      #pragma unroll
      for (int ts = 0; ts < 8; ++ts) s += red[ts][g][d];
      atomicAdd(&attn_out[((size_t)b * HH + kv * GG + g) * DD + d], s);
    }
  }
}

// ============ K8: out = attn_out @ Wo^T, 32 rows/block, 8 thr/row ============
__global__ __launch_bounds__(256) void outproj_kernel(
    const float* __restrict__ attn_out, const float* __restrict__ Wo,
    float* __restrict__ out)
{
  __shared__ float al[EE];
  int b = blockIdx.x >> 7, seg = blockIdx.x & 127;
  int tid = threadIdx.x;
  for (int i = tid; i < EE; i += 256) al[i] = attn_out[(size_t)b * EE + i];
  __syncthreads();
  int rloc = tid >> 3, sub = tid & 7;
  int e = seg * 32 + rloc;
  const float* wr = Wo + (size_t)e * EE + sub * 512;
  const float* av = al + sub * 512;
  float acc = 0.f;
  for (int j = 0; j < 512; j += 4) {
    float4 w4 = *(const float4*)(wr + j);
    float4 a4 = *(const float4*)(av + j);
    acc = fmaf(w4.x, a4.x, acc);
    acc = fmaf(w4.y, a4.y, acc);
    acc = fmaf(w4.z, a4.z, acc);
    acc = fmaf(w4.w, a4.w, acc);
  }
  acc += __shfl_xor(acc, 1);
  acc += __shfl_xor(acc, 2);
  acc += __shfl_xor(acc, 4);
  if (sub == 0) out[(size_t)b * EE + e] = acc;
}

// ===================== launcher =====================
extern "C" void kernel_launch(void* const* d_in, const int* in_sizes, int n_in,
                              void* d_out, int out_size, void* d_ws, size_t ws_size,
                              hipStream_t stream)
{
  const float* hs    = (const float*)d_in[0];
  const float* cosb  = (const float*)d_in[1];
  const float* sinb  = (const float*)d_in[2];
  const float* pk    = (const float*)d_in[3];
  const float* pv    = (const float*)d_in[4];
  const float* amask = (const float*)d_in[5];
  const float* Wq    = (const float*)d_in[6];
  const float* Wk    = (const float*)d_in[7];
  const float* Wv    = (const float*)d_in[8];
  const float* Wo    = (const float*)d_in[9];
  const float* Sp    = (const float*)d_in[10];
  float* out = (float*)d_out;
  float* ws = (float*)d_ws;

  float* q_rope = ws + OFF_Q;
  float* k_new  = ws + OFF_KN;
  float* v_new  = ws + OFF_VN;
  float* maskf  = ws + OFF_MASKF;
  float* qoval  = ws + OFF_QOV;
  float* attn_o = ws + OFF_AO;
  int*   pos    = (int*)(ws + OFF_INT);
  int*   oidx   = pos + BB * HKV * DD;
  _Float16* qsfT = (_Float16*)(ws + OFF_QSF);
  _Float16* Sfhi = (_Float16*)(ws + OFF_SFRAG);
  _Float16* Sflo = Sfhi + 65536;
  float* qkvp   = ws + OFF_QKVP;
  float* scorep = ws + OFF_SCOREP;
  float* logits = ws + OFF_LOGITS;

  int k1_grid = BB * NSEG * ESPLIT + BB * HKV * 64 + 16;   // 2832
  k1_kernel<<<k1_grid, 256, 0, stream>>>(hs, pk, Wq, Wk, Wv, Sp,
                                         qkvp, scorep, Sfhi, Sflo);
  qkv_finalize_kernel<<<96, 256, 0, stream>>>(qkvp, cosb, sinb,
                                              q_rope, k_new, v_new);
  topk_kernel<<<BB * HKV, 128, 0, stream>>>(scorep, k_new, maskf, pos, oidx);
  qs_kernel<<<BB * HKV * GG, 256, 0, stream>>>(q_rope, maskf, Sp, oidx, qsfT, qoval);
  logits_kernel<<<BB * HKV * NT2, 256, 0, stream>>>(pk, k_new, Sfhi, Sflo, qsfT,
                                                    qoval, pos, amask, logits);
  softmax_kernel<<<BB * HKV * GG, 256, 0, stream>>>(logits, attn_o);
  wv_kernel<<<BB * HKV * WCH, 256, 0, stream>>>(pv, v_new, logits, attn_o);
  outproj_kernel<<<BB * 128, 256, 0, stream>>>(attn_o, Wo, out);
}

// Round 4
// 540.837 us; speedup vs baseline: 1.9682x; 1.0787x over previous
//
#include <hip/hip_runtime.h>
#include <math.h>

#define BB 4
#define TP 8192
#define TT 8193          // TP + 1
#define EE 4096
#define HH 32
#define HKV 8
#define DD 128
#define MM 256
#define GG 4             // H / HKV
#define NSEG 48          // H + 2*HKV row-segments of 128
#define ESPLIT 8         // E-split for qkv GEMV (512-col chunks)
#define TB 64            // t-rows per logits block
#define NT2 129          // ceil(8193/64)
#define WCH 65           // ceil(8193/128) value chunks per (b,kv)

#define CJL 0.0048957583420918762f     // sqrt(pi/2)/256
#define RSQRT_D 0.08838834764831845f   // 1/sqrt(128)
#define NEG_HUGE -3.402823466e38f

#define KSTR 136         // kt row stride in f16
#define SSTR 276         // sign row stride in f16 (552 B: conflict-free b16 writes)

typedef _Float16 f16x8 __attribute__((ext_vector_type(8)));
typedef _Float16 f16x4 __attribute__((ext_vector_type(4)));
typedef float f32x4 __attribute__((ext_vector_type(4)));

// ---- workspace layout (float offsets); qkvp/scorep die before logits and
// are overlaid by the logits buffer (stream-ordered, safe) ----
#define OFF_Q      0            // q_rope   B*H*D    = 16384
#define OFF_KN     16384        // k_new    B*HKV*D  = 4096
#define OFF_VN     20480        // v_new               4096
#define OFF_MASKF  24576        // 1-omask             4096
#define OFF_QOV    28672        // q at outlier dims   1024
#define OFF_AO     29696        // attn out B*H*D    = 16384 (zeroed in softmax)
#define OFF_INT    46080        // ints: pos (4096), oidx (256) -> 4352 floats
#define OFF_QSF    50432        // qs f16 padded [bk][16][256] -> 65536 fl reserved
#define OFF_SFRAG  115968       // S frags hi/lo (f16) -> 65536 fl reserved
#define OFF_QKVP   181504       // qkv partials [8][48][4][128] = 196608 fl
#define OFF_SCOREP 378112       // score partials [64][32][128] = 262144 fl
#define OFF_LOGITS 181504       // B*HKV*G*T = 1048704 fl  (overlays qkvp+scorep)

#define QKV_BLKS  (NSEG * ESPLIT)          // 384
#define SCORE_BLKS (BB * HKV * 64)         // 2048

// ============ K1: fused qkv-partial GEMV (all-b) + score + S-frag prep ======
__global__ __launch_bounds__(256) void k1_kernel(
    const float* __restrict__ hs, const float* __restrict__ pk,
    const float* __restrict__ Wq, const float* __restrict__ Wk,
    const float* __restrict__ Wv, const float* __restrict__ Sp,
    float* __restrict__ qkvp, float* __restrict__ scorep,
    _Float16* __restrict__ Sfhi, _Float16* __restrict__ Sflo)
{
  __shared__ float smem[3072];   // 12 KB, carved per branch
  int bid = blockIdx.x, tid = threadIdx.x;
  if (bid < QKV_BLKS) {
    // ---- qkv partial: (seg, c); 128 rows x 512-E-chunk x ALL 4 b ----
    int c = bid & 7;
    int seg = bid >> 3;
    const float* W;
    if (seg < HH)            W = Wq + (size_t)seg * DD * EE;
    else if (seg < HH + HKV) W = Wk + (size_t)(seg - HH) * DD * EE;
    else                     W = Wv + (size_t)(seg - HH - HKV) * DD * EE;
    float* hsl  = smem;          // [4][512]
    float* sred = smem + 2048;   // [2][4][128] -> 1024 fl
    for (int i = tid; i < 4 * 512; i += 256) {
      int b = i >> 9, col = i & 511;
      hsl[i] = hs[b * EE + c * 512 + col];
    }
    __syncthreads();
    int row = tid & 127, half = tid >> 7;
    const float* wr = W + (size_t)row * EE + c * 512 + half * 256;
    float4 acc[BB];
    #pragma unroll
    for (int b = 0; b < BB; ++b) acc[b] = make_float4(0.f, 0.f, 0.f, 0.f);
    for (int j = 0; j < 256; j += 4) {
      float4 w4 = *(const float4*)(wr + j);
      #pragma unroll
      for (int b = 0; b < BB; ++b) {
        float4 a4 = *(const float4*)&hsl[b * 512 + half * 256 + j];  // broadcast
        acc[b].x = fmaf(w4.x, a4.x, acc[b].x);
        acc[b].y = fmaf(w4.y, a4.y, acc[b].y);
        acc[b].z = fmaf(w4.z, a4.z, acc[b].z);
        acc[b].w = fmaf(w4.w, a4.w, acc[b].w);
      }
    }
    #pragma unroll
    for (int b = 0; b < BB; ++b)
      sred[(half * BB + b) * DD + row] = (acc[b].x + acc[b].y) + (acc[b].z + acc[b].w);
    __syncthreads();
    for (int i = tid; i < BB * DD; i += 256) {
      int b = i >> 7, d = i & 127;
      qkvp[(((size_t)c * NSEG + seg) * BB + b) * DD + d] =
          sred[b * DD + d] + sred[(BB + b) * DD + d];
    }
  } else if (bid < QKV_BLKS + SCORE_BLKS) {
    // ---- score partial: sum_t |K[t,d]| over a 128-t chunk, float4 ----
    int id = bid - QKV_BLKS;
    int chunk = id & 63, bk = id >> 6;
    const float* base = pk + (size_t)bk * TP * DD + (size_t)chunk * 128 * DD;
    int tsub = tid >> 5, d4 = (tid & 31) * 4;
    float4 a = make_float4(0.f, 0.f, 0.f, 0.f);
    for (int t = tsub; t < 128; t += 8) {
      float4 v = *(const float4*)(base + (size_t)t * DD + d4);
      a.x += fabsf(v.x); a.y += fabsf(v.y); a.z += fabsf(v.z); a.w += fabsf(v.w);
    }
    *(float4*)&smem[tsub * DD + d4] = a;
    __syncthreads();
    if (tid < DD) {
      float s = 0.f;
      #pragma unroll
      for (int u = 0; u < 8; ++u) s += smem[u * DD + tid];
      scorep[((size_t)chunk * BB * HKV + bk) * DD + tid] = s;
    }
  } else {
    // ---- sprep: S -> f16 hi/lo fragments in MFMA-lane-swizzled layout ----
    int id = bid - QKV_BLKS - SCORE_BLKS;   // 0..15 = mt*4+ks
    int mt = id >> 2, ks = id & 3;
    int w = tid >> 6, q = (tid >> 4) & 3, l15 = tid & 15;
    f16x8 hi, lo;
    #pragma unroll
    for (int j = 0; j < 8; ++j) {
      float s = Sp[(ks * 32 + q * 8 + j) * MM + w * 64 + mt * 16 + l15];
      _Float16 h = (_Float16)s;
      hi[j] = h;
      lo[j] = (_Float16)(s - (float)h);
    }
    *(f16x8*)&Sfhi[(size_t)(id * 256 + tid) * 8] = hi;
    *(f16x8*)&Sflo[(size_t)(id * 256 + tid) * 8] = lo;
  }
}

// ============ K2: qkv finalize — sum 8 partials + RoPE ============
__global__ __launch_bounds__(256) void qkv_finalize_kernel(
    const float* __restrict__ qkvp, const float* __restrict__ cosb,
    const float* __restrict__ sinb, float* __restrict__ q_out,
    float* __restrict__ k_out, float* __restrict__ v_out)
{
  int gid = blockIdx.x * 256 + threadIdx.x;   // < 24576
  int b = gid / 6144;
  int r = gid - b * 6144;
  int seg = r >> 7, d = r & 127;
  float sum = 0.f;
  #pragma unroll
  for (int c = 0; c < ESPLIT; ++c)
    sum += qkvp[(((size_t)c * NSEG + seg) * BB + b) * DD + d];
  if (seg >= HH + HKV) {
    v_out[((size_t)b * HKV + (seg - HH - HKV)) * DD + d] = sum;
  } else {
    float part = 0.f;
    int dp = d ^ 64;
    #pragma unroll
    for (int c = 0; c < ESPLIT; ++c)
      part += qkvp[(((size_t)c * NSEG + seg) * BB + b) * DD + dp];
    float cc = cosb[b * DD + d], ss = sinb[b * DD + d];
    float other = (d < 64) ? -part : part;
    float rv = fmaf(sum, cc, other * ss);
    if (seg < HH) q_out[((size_t)b * HH + seg) * DD + d] = rv;
    else          k_out[((size_t)b * HKV + (seg - HH)) * DD + d] = rv;
  }
}

// ============ K3: top-8 outlier channels ============
__global__ __launch_bounds__(128) void topk_kernel(
    const float* __restrict__ scorep, const float* __restrict__ k_new,
    float* __restrict__ maskf, int* __restrict__ pos, int* __restrict__ oidx)
{
  int bk = blockIdx.x;
  int tid = threadIdx.x;
  __shared__ float sv[DD];
  __shared__ int si[DD];
  float cur = 0.f;
  for (int c = 0; c < 64; ++c)
    cur += scorep[((size_t)c * BB * HKV + bk) * DD + tid];
  cur += fabsf(k_new[bk * DD + tid]);
  maskf[bk * DD + tid] = 1.f;
  pos[bk * DD + tid] = -1;
  for (int o = 0; o < 8; ++o) {
    sv[tid] = cur; si[tid] = tid;
    __syncthreads();
    for (int st = 64; st > 0; st >>= 1) {
      if (tid < st) {
        float a = sv[tid], c2 = sv[tid + st];
        int ia = si[tid], ic = si[tid + st];
        if (c2 > a || (c2 == a && ic < ia)) { sv[tid] = c2; si[tid] = ic; }
      }
      __syncthreads();
    }
    int mi = si[0];
    __syncthreads();
    if (tid == 0) oidx[bk * 8 + o] = mi;
    if (tid == mi) { pos[bk * DD + tid] = o; maskf[bk * DD + tid] = 0.f; cur = NEG_HUGE; }
  }
}

// ============ K4: qs = q_in @ S (f16 padded) + q outlier values ============
__global__ __launch_bounds__(256) void qs_kernel(
    const float* __restrict__ q_rope, const float* __restrict__ maskf,
    const float* __restrict__ Sp, const int* __restrict__ oidx,
    _Float16* __restrict__ qsfT, float* __restrict__ qoval)
{
  int bkg = blockIdx.x;
  int bk = bkg >> 2, g = bkg & 3;
  int b = bk >> 3, kv = bk & 7;
  __shared__ float qin[DD];
  __shared__ float qfull[DD];
  if (threadIdx.x < DD) {
    float qv = q_rope[((size_t)b * HH + kv * GG + g) * DD + threadIdx.x];
    qfull[threadIdx.x] = qv;
    qin[threadIdx.x] = qv * maskf[bk * DD + threadIdx.x];
  }
  __syncthreads();
  int m = threadIdx.x;
  float acc = 0.f;
  for (int d = 0; d < DD; ++d)
    acc = fmaf(qin[d], Sp[d * MM + m], acc);
  qsfT[((size_t)bk * 16 + g) * MM + m] = (_Float16)acc;
  if (g == 0) {
    #pragma unroll
    for (int n = 4; n < 16; ++n)
      qsfT[((size_t)bk * 16 + n) * MM + m] = (_Float16)0.f;
  }
  if (threadIdx.x < 8)
    qoval[bkg * 8 + threadIdx.x] = qfull[oidx[bk * 8 + threadIdx.x]];
}

// ============ K5: logits via f16 hi/lo MFMA, S streamed per-ks ============
__global__ __launch_bounds__(256) void logits_kernel(
    const float* __restrict__ pk, const float* __restrict__ k_new,
    const _Float16* __restrict__ Sfhi, const _Float16* __restrict__ Sflo,
    const _Float16* __restrict__ qsfT, const float* __restrict__ qoval,
    const int* __restrict__ pos, const float* __restrict__ amask,
    float* __restrict__ logits)
{
  __shared__ union {
    struct { _Float16 hi[TB * KSTR]; _Float16 lo[TB * KSTR]; } k;  // 34816 B
    _Float16 ssg[TB * SSTR];                                       // 35328 B
  } u;
  __shared__ float norm2[TB];
  __shared__ float koutl[TB][8];
  __shared__ float qovl[GG][8];

  int bk = blockIdx.x / NT2;
  int tile = blockIdx.x % NT2;
  int b = bk >> 3;
  int t0 = tile * TB;
  int tid = threadIdx.x;
  int l15 = tid & 15;
  int q   = (tid >> 4) & 3;
  int w   = tid >> 6;
  int mb  = w * 64;

  if (tid < 32) ((float*)qovl)[tid] = qoval[bk * 32 + tid];

  // per-lane outlier positions for its 4 d's (constant across t-rows)
  int d4 = (tid & 31) * 4;
  int p4[4];
  #pragma unroll
  for (int j = 0; j < 4; ++j) p4[j] = pos[bk * DD + d4 + j];

  // ---- stage key tile: zero outliers, save originals, norms, hi/lo cvt ----
  #pragma unroll
  for (int iter = 0; iter < 8; ++iter) {
    int tl = iter * 8 + (tid >> 5);
    int tg = t0 + tl;
    float4 kv4 = make_float4(0.f, 0.f, 0.f, 0.f);
    if (tg < TP)       kv4 = *(const float4*)(pk + ((size_t)bk * TP + tg) * DD + d4);
    else if (tg == TP) kv4 = *(const float4*)(k_new + (size_t)bk * DD + d4);
    float vals[4] = {kv4.x, kv4.y, kv4.z, kv4.w};
    float nrm = 0.f;
    f16x4 hi4, lo4;
    #pragma unroll
    for (int j = 0; j < 4; ++j) {
      if (p4[j] >= 0) { koutl[tl][p4[j]] = vals[j]; vals[j] = 0.f; }
      nrm = fmaf(vals[j], vals[j], nrm);
      _Float16 h = (_Float16)vals[j];
      hi4[j] = h;
      lo4[j] = (_Float16)(vals[j] - (float)h);
    }
    *(f16x4*)&u.k.hi[tl * KSTR + d4] = hi4;
    *(f16x4*)&u.k.lo[tl * KSTR + d4] = lo4;
    #pragma unroll
    for (int off = 16; off > 0; off >>= 1) nrm += __shfl_xor(nrm, off);
    if ((tid & 31) == 0) norm2[tl] = nrm;
  }
  __syncthreads();

  // ---- MFMA loop: ks-chunked S streaming (8 frags resident at a time) ----
  f32x4 acc[4][4];
  #pragma unroll
  for (int ts = 0; ts < 4; ++ts)
    #pragma unroll
    for (int mt = 0; mt < 4; ++mt)
      acc[ts][mt] = (f32x4){0.f, 0.f, 0.f, 0.f};

  const f16x8* SH = (const f16x8*)Sfhi;
  const f16x8* SL = (const f16x8*)Sflo;
  #pragma unroll
  for (int ks = 0; ks < 4; ++ks) {
    f16x8 sh[4], sl[4], ah[4], al[4];
    #pragma unroll
    for (int mt = 0; mt < 4; ++mt) {
      sh[mt] = SH[(size_t)(mt * 4 + ks) * 256 + tid];
      sl[mt] = SL[(size_t)(mt * 4 + ks) * 256 + tid];
    }
    #pragma unroll
    for (int ts = 0; ts < 4; ++ts) {
      ah[ts] = *(const f16x8*)&u.k.hi[(ts * 16 + l15) * KSTR + ks * 32 + q * 8];
      al[ts] = *(const f16x8*)&u.k.lo[(ts * 16 + l15) * KSTR + ks * 32 + q * 8];
    }
    #pragma unroll
    for (int ts = 0; ts < 4; ++ts)
      #pragma unroll
      for (int mt = 0; mt < 4; ++mt) {
        acc[ts][mt] = __builtin_amdgcn_mfma_f32_16x16x32_f16(ah[ts], sh[mt], acc[ts][mt], 0, 0, 0);
        acc[ts][mt] = __builtin_amdgcn_mfma_f32_16x16x32_f16(al[ts], sh[mt], acc[ts][mt], 0, 0, 0);
        acc[ts][mt] = __builtin_amdgcn_mfma_f32_16x16x32_f16(ah[ts], sl[mt], acc[ts][mt], 0, 0, 0);
      }
  }
  __syncthreads();   // done reading kt; LDS reused for sign matrix

  // ---- write sign matrix (C-layout -> [t][m] f16) ----
  #pragma unroll
  for (int ts = 0; ts < 4; ++ts)
    #pragma unroll
    for (int mt = 0; mt < 4; ++mt)
      #pragma unroll
      for (int r = 0; r < 4; ++r) {
        int tl = ts * 16 + q * 4 + r;
        int mm = mb + mt * 16 + l15;
        u.ssg[tl * SSTR + mm] = acc[ts][mt][r] >= 0.f ? (_Float16)1.f : (_Float16)-1.f;
      }
  __syncthreads();

  // ---- est = sign @ qs^T via MFMA; wave w handles t in [16w, 16w+16) ----
  f32x4 eacc = (f32x4){0.f, 0.f, 0.f, 0.f};
  const _Float16* qrow = qsfT + ((size_t)bk * 16 + l15) * MM;
  #pragma unroll
  for (int ks = 0; ks < 8; ++ks) {
    f16x8 as = *(const f16x8*)&u.ssg[(16 * w + l15) * SSTR + ks * 32 + q * 8];
    f16x8 bq = *(const f16x8*)&qrow[ks * 32 + q * 8];
    eacc = __builtin_amdgcn_mfma_f32_16x16x32_f16(as, bq, eacc, 0, 0, 0);
  }

  // ---- assemble logits: lanes with l15 < 4 hold est for g = l15 ----
  if (l15 < 4) {
    int g = l15;
    #pragma unroll
    for (int r = 0; r < 4; ++r) {
      int tl = 16 * w + q * 4 + r;
      int tg = t0 + tl;
      if (tg < TT) {
        float ex = 0.f;
        #pragma unroll
        for (int o = 0; o < 8; ++o) ex = fmaf(qovl[g][o], koutl[tl][o], ex);
        float logit = fmaf(eacc[r] * CJL, sqrtf(norm2[tl]), ex) * RSQRT_D;
        logit += (1.f - amask[b * TT + tg]) * NEG_HUGE;
        logits[((size_t)(bk * GG + g)) * TT + tg] = logit;
      }
    }
  }
}

// ============ K6: softmax over T per (b,kv,g) + zero attn_o ============
__global__ __launch_bounds__(256) void softmax_kernel(
    float* __restrict__ logits, float* __restrict__ attn_o)
{
  int row = blockIdx.x;
  float* L = logits + (size_t)row * TT;
  int tid = threadIdx.x;
  int lane = tid & 63, wid = tid >> 6;
  __shared__ float red[8];
  if (tid < 128) attn_o[(size_t)row * DD + tid] = 0.f;
  float mx = NEG_HUGE;
  for (int i = tid; i < TT; i += 256) mx = fmaxf(mx, L[i]);
  #pragma unroll
  for (int off = 32; off > 0; off >>= 1) mx = fmaxf(mx, __shfl_xor(mx, off));
  if (lane == 0) red[wid] = mx;
  __syncthreads();
  if (tid == 0) red[4] = fmaxf(fmaxf(red[0], red[1]), fmaxf(red[2], red[3]));
  __syncthreads();
  mx = red[4];
  float sum = 0.f;
  for (int i = tid; i < TT; i += 256) sum += expf(L[i] - mx);
  #pragma unroll
  for (int off = 32; off > 0; off >>= 1) sum += __shfl_xor(sum, off);
  if (lane == 0) red[wid] = sum;
  __syncthreads();
  if (tid == 0) red[5] = (red[0] + red[1]) + (red[2] + red[3]);
  __syncthreads();
  float inv = 1.f / red[5];
  for (int i = tid; i < TT; i += 256) L[i] = expf(L[i] - mx) * inv;
}

// ============ K7: out_head = w @ V, w staged in LDS ============
__global__ __launch_bounds__(256) void wv_kernel(
    const float* __restrict__ pv, const float* __restrict__ v_new,
    const float* __restrict__ w, float* __restrict__ attn_out)
{
  __shared__ float wl[GG * 128];     // 2 KB
  __shared__ float red[8][GG][DD];   // 16 KB
  int bk = blockIdx.x / WCH;
  int chunk = blockIdx.x % WCH;
  int b = bk >> 3, kv = bk & 7;
  int t0 = chunk * 128;
  const float* wbase = w + (size_t)bk * GG * TT;
  for (int i = threadIdx.x; i < GG * 128; i += 256) {
    int g = i >> 7, tloc = i & 127;
    int t = t0 + tloc;
    wl[i] = (t < TT) ? wbase[g * TT + t] : 0.f;
  }
  __syncthreads();
  int tsub = threadIdx.x >> 5;
  int d4 = (threadIdx.x & 31) * 4;
  int tend = (t0 + 128 < TT) ? t0 + 128 : TT;
  float4 acc[GG];
  #pragma unroll
  for (int g = 0; g < GG; ++g) acc[g] = make_float4(0.f, 0.f, 0.f, 0.f);
  for (int t = t0 + tsub; t < tend; t += 8) {
    float4 v = (t < TP) ? *(const float4*)(pv + ((size_t)bk * TP + t) * DD + d4)
                        : *(const float4*)(v_new + (size_t)bk * DD + d4);
    #pragma unroll
    for (int g = 0; g < GG; ++g) {
      float wv = wl[g * 128 + (t - t0)];   // broadcast
      acc[g].x = fmaf(wv, v.x, acc[g].x);
      acc[g].y = fmaf(wv, v.y, acc[g].y);
      acc[g].z = fmaf(wv, v.z, acc[g].z);
      acc[g].w = fmaf(wv, v.w, acc[g].w);
    }
  }
  #pragma unroll
  for (int g = 0; g < GG; ++g) *(float4*)&red[tsub][g][d4] = acc[g];
  __syncthreads();
  if (threadIdx.x < DD) {
    int d = threadIdx.x;
    #pragma unroll
    for (int g = 0; g < GG; ++g) {
      float s = 0.f;
      #pragma unroll
      for (int ts = 0; ts < 8; ++ts) s += red[ts][g][d];
      atomicAdd(&attn_out[((size_t)b * HH + kv * GG + g) * DD + d], s);
    }
  }
}

// ============ K8: out = attn_out @ Wo^T, Wo read once (all 4 b) ============
// grid 256: each block = 16 e-rows x all b. al padded [16][260] per b.
__global__ __launch_bounds__(256) void outproj_kernel(
    const float* __restrict__ attn_out, const float* __restrict__ Wo,
    float* __restrict__ out)
{
  __shared__ float al[BB][16][260];   // 66560 B, pad breaks stride-256 conflicts
  int seg = blockIdx.x;
  int tid = threadIdx.x;
  for (int i = tid; i < BB * EE; i += 256) {
    int b = i >> 12, col = i & 4095;
    al[b][col >> 8][col & 255] = attn_out[(size_t)b * EE + col];
  }
  __syncthreads();
  int rloc = tid >> 4, sub = tid & 15;
  int e = seg * 16 + rloc;
  const float* wr = Wo + (size_t)e * EE + sub * 256;
  float acc[BB] = {0.f, 0.f, 0.f, 0.f};
  for (int j = 0; j < 256; j += 4) {
    float4 w4 = *(const float4*)(wr + j);
    #pragma unroll
    for (int b = 0; b < BB; ++b) {
      float4 a4 = *(const float4*)&al[b][sub][j];
      acc[b] = fmaf(w4.x, a4.x, acc[b]);
      acc[b] = fmaf(w4.y, a4.y, acc[b]);
      acc[b] = fmaf(w4.z, a4.z, acc[b]);
      acc[b] = fmaf(w4.w, a4.w, acc[b]);
    }
  }
  #pragma unroll
  for (int b = 0; b < BB; ++b) {
    acc[b] += __shfl_xor(acc[b], 1);
    acc[b] += __shfl_xor(acc[b], 2);
    acc[b] += __shfl_xor(acc[b], 4);
    acc[b] += __shfl_xor(acc[b], 8);
  }
  if (sub == 0) {
    #pragma unroll
    for (int b = 0; b < BB; ++b)
      out[(size_t)b * EE + e] = acc[b];
  }
}

// ===================== launcher =====================
extern "C" void kernel_launch(void* const* d_in, const int* in_sizes, int n_in,
                              void* d_out, int out_size, void* d_ws, size_t ws_size,
                              hipStream_t stream)
{
  const float* hs    = (const float*)d_in[0];
  const float* cosb  = (const float*)d_in[1];
  const float* sinb  = (const float*)d_in[2];
  const float* pk    = (const float*)d_in[3];
  const float* pv    = (const float*)d_in[4];
  const float* amask = (const float*)d_in[5];
  const float* Wq    = (const float*)d_in[6];
  const float* Wk    = (const float*)d_in[7];
  const float* Wv    = (const float*)d_in[8];
  const float* Wo    = (const float*)d_in[9];
  const float* Sp    = (const float*)d_in[10];
  float* out = (float*)d_out;
  float* ws = (float*)d_ws;

  float* q_rope = ws + OFF_Q;
  float* k_new  = ws + OFF_KN;
  float* v_new  = ws + OFF_VN;
  float* maskf  = ws + OFF_MASKF;
  float* qoval  = ws + OFF_QOV;
  float* attn_o = ws + OFF_AO;
  int*   pos    = (int*)(ws + OFF_INT);
  int*   oidx   = pos + BB * HKV * DD;
  _Float16* qsfT = (_Float16*)(ws + OFF_QSF);
  _Float16* Sfhi = (_Float16*)(ws + OFF_SFRAG);
  _Float16* Sflo = Sfhi + 65536;
  float* qkvp   = ws + OFF_QKVP;
  float* scorep = ws + OFF_SCOREP;
  float* logits = ws + OFF_LOGITS;

  int k1_grid = QKV_BLKS + SCORE_BLKS + 16;   // 2448
  k1_kernel<<<k1_grid, 256, 0, stream>>>(hs, pk, Wq, Wk, Wv, Sp,
                                         qkvp, scorep, Sfhi, Sflo);
  qkv_finalize_kernel<<<96, 256, 0, stream>>>(qkvp, cosb, sinb,
                                              q_rope, k_new, v_new);
  topk_kernel<<<BB * HKV, 128, 0, stream>>>(scorep, k_new, maskf, pos, oidx);
  qs_kernel<<<BB * HKV * GG, 256, 0, stream>>>(q_rope, maskf, Sp, oidx, qsfT, qoval);
  logits_kernel<<<BB * HKV * NT2, 256, 0, stream>>>(pk, k_new, Sfhi, Sflo, qsfT,
                                                    qoval, pos, amask, logits);
  softmax_kernel<<<BB * HKV * GG, 256, 0, stream>>>(logits, attn_o);
  wv_kernel<<<BB * HKV * WCH, 256, 0, stream>>>(pv, v_new, logits, attn_o);
  outproj_kernel<<<256, 256, 0, stream>>>(attn_o, Wo, out);
}